// Round 4
// baseline (867.878 us; speedup 1.0000x reference)
//
#include <hip/hip_runtime.h>
#include <hip/hip_bf16.h>

// ---------------------------------------------------------------------------
// ArcFace PartialFC loss, fused:
//   k1: normalize embeddings -> f32 copy (exact target path) + bf16 copy (GEMM)
//   k2: W staged as f32 via global_load_lds (DMA, max MLP), double-buffered
//       32KB K-chunks, 2-phase pipeline; XOR-swizzled via pre-swizzled global
//       source + swizzled ds_read; bf16 cvt at fragment read; fused ||w||^2
//       LDS pass; fused exp(64*cos-64) partials -> atomicAdd gsum[512].
//   k3: exact-f32 target cosine per row, arcface margin, swap target term,
//       per-row NLL -> atomic sum + valid count
//   k4: loss = nll_sum / max(count,1)
// (Resubmission of round-2 source: bench infra timed out, no measurement.)
// ---------------------------------------------------------------------------

#define D_SZ 512
#define B_SZ 512
#define C_SZ 200000
#define BM   64          // C-rows per block; 200000/64 = 3125 exactly
#define CHK  128         // K elems (f32) per chunk
#define CHB  (CHK * 4)   // bytes per row per chunk (512)
#define NCHK (D_SZ / CHK)
#define SCL  64.0f
#define MRG  0.5f

typedef __attribute__((ext_vector_type(8))) short  bf16x8;
typedef __attribute__((ext_vector_type(8))) __bf16 bf16x8f;
typedef __attribute__((ext_vector_type(4))) float  f32x4;

__device__ __forceinline__ ushort f2bf_bits(float x) {
  __bf16 h = (__bf16)x;
  return __builtin_bit_cast(ushort, h);
}

__device__ __forceinline__ bf16x8 cvt8(float4 a, float4 b) {
  bf16x8f t;
  t[0] = (__bf16)a.x; t[1] = (__bf16)a.y; t[2] = (__bf16)a.z; t[3] = (__bf16)a.w;
  t[4] = (__bf16)b.x; t[5] = (__bf16)b.y; t[6] = (__bf16)b.z; t[7] = (__bf16)b.w;
  return __builtin_bit_cast(bf16x8, t);
}

// --- k1: row-normalize embeddings. 128 blocks x 256 threads (1 wave = 1 row).
__global__ void k_norm_emb(const float* __restrict__ emb,
                           float* __restrict__ nf32,
                           ushort* __restrict__ nbf) {
  const int row  = blockIdx.x * 4 + (threadIdx.x >> 6);
  const int lane = threadIdx.x & 63;
  const float4* r4 = (const float4*)(emb + (size_t)row * D_SZ);
  float4 a = r4[lane];
  float4 b = r4[lane + 64];
  float ss = a.x*a.x + a.y*a.y + a.z*a.z + a.w*a.w
           + b.x*b.x + b.y*b.y + b.z*b.z + b.w*b.w;
#pragma unroll
  for (int off = 32; off; off >>= 1) ss += __shfl_xor(ss, off, 64);
  const float s = 1.0f / fmaxf(sqrtf(ss), 1e-12f);
  a.x *= s; a.y *= s; a.z *= s; a.w *= s;
  b.x *= s; b.y *= s; b.z *= s; b.w *= s;
  float4* o4 = (float4*)(nf32 + (size_t)row * D_SZ);
  o4[lane] = a; o4[lane + 64] = b;
  ushort4 ua, ub;
  ua.x = f2bf_bits(a.x); ua.y = f2bf_bits(a.y); ua.z = f2bf_bits(a.z); ua.w = f2bf_bits(a.w);
  ub.x = f2bf_bits(b.x); ub.y = f2bf_bits(b.y); ub.z = f2bf_bits(b.z); ub.w = f2bf_bits(b.w);
  ushort4* ob = (ushort4*)(nbf + (size_t)row * D_SZ);
  ob[lane] = ua; ob[lane + 64] = ub;
}

// Stage one 64xCHK f32 chunk into LDS via global_load_lds (linear dest,
// inverse-swizzled per-lane source). Wave w stages rows [w*8, w*8+8);
// each inst = 1KB = 2 rows (row = 512B), lane l -> row +(l>>5), chunk l&31.
__device__ __forceinline__ void stage_chunk(const float* __restrict__ W,
                                            size_t c0, int ch, float* buf,
                                            int wave, int lane) {
  const int rl = lane >> 5;
  const int cp = lane & 31;
#pragma unroll
  for (int i = 0; i < 4; ++i) {
    const int r  = wave * 8 + 2 * i + rl;
    const int cc = cp ^ (r & 7);          // inverse of read-side XOR
    const float* src = W + (c0 + r) * (size_t)D_SZ + ch * CHK + cc * 4;
    float* dst = buf + (wave * 8 + 2 * i) * CHK;   // wave-uniform base
    __builtin_amdgcn_global_load_lds(
        (const __attribute__((address_space(1))) void*)src,
        (__attribute__((address_space(3))) void*)dst, 16, 0, 0);
  }
}

// --- k2: DMA-staged GEMM + fused softmax-denominator partials.
// grid 3125 x 512. Wave w owns B-cols [64w, 64w+64), all 64 C-rows.
__global__ __launch_bounds__(512, 4)   // 128 VGPR cap -> 2 blocks/CU
void k_gemm_lse(const float* __restrict__ W,
                const ushort* __restrict__ E,
                float* __restrict__ gsum) {
  __shared__ float bufs[2][BM * CHK];   // 2 x 32 KiB
  __shared__ float wlds[BM];
  const int tid  = threadIdx.x;
  const int wave = tid >> 6;
  const int lane = tid & 63;
  const int l15  = lane & 15;
  const int lk   = lane >> 4;
  const size_t c0 = (size_t)blockIdx.x * BM;
  const ushort* ebase = E + (size_t)(wave * 64 + l15) * D_SZ + lk * 8;
  const int nr = tid >> 3, nj = tid & 7;          // norm-pass row / slot

  f32x4 acc[4][4];
  const f32x4 z = {0.f, 0.f, 0.f, 0.f};
#pragma unroll
  for (int ci = 0; ci < 4; ++ci)
#pragma unroll
    for (int bi = 0; bi < 4; ++bi) acc[ci][bi] = z;
  float wn = 0.f;

  stage_chunk(W, c0, 0, bufs[0], wave, lane);
  __syncthreads();

#pragma unroll
  for (int ch = 0; ch < NCHK; ++ch) {
    float* cur = bufs[ch & 1];
    if (ch + 1 < NCHK)
      stage_chunk(W, c0, ch + 1, bufs[(ch + 1) & 1], wave, lane);

    // ||w||^2 accumulation from staged f32 (swizzled reads)
    {
      const char* rowp = (const char*)cur + nr * CHB;
      const int sw2 = (nr & 7) << 4;
#pragma unroll
      for (int i = 0; i < 4; ++i) {
        float4 x = *(const float4*)(rowp + (((i * 8 + nj) * 16) ^ sw2));
        wn += x.x*x.x + x.y*x.y + x.z*x.z + x.w*x.w;
      }
    }

    // MFMA over this chunk (4 K-steps of 32)
    const int sw = (l15 & 7) << 4;
#pragma unroll
    for (int ks = 0; ks < 4; ++ks) {
      bf16x8 wf[4], ef[4];
      const int kb = ks * 128 + lk * 32;
#pragma unroll
      for (int ci = 0; ci < 4; ++ci) {
        const char* rowp = (const char*)cur + (ci * 16 + l15) * CHB;
        float4 x0 = *(const float4*)(rowp + (kb ^ sw));
        float4 x1 = *(const float4*)(rowp + ((kb + 16) ^ sw));
        wf[ci] = cvt8(x0, x1);
      }
#pragma unroll
      for (int bi = 0; bi < 4; ++bi)
        ef[bi] = *(const bf16x8*)(ebase + (size_t)(bi * 16) * D_SZ
                                  + ch * CHK + ks * 32);
#pragma unroll
      for (int ci = 0; ci < 4; ++ci)
#pragma unroll
        for (int bi = 0; bi < 4; ++bi)
          acc[ci][bi] = __builtin_amdgcn_mfma_f32_16x16x32_bf16(
              wf[ci], ef[bi], acc[ci][bi], 0, 0, 0);
    }
    __syncthreads();   // next chunk's DMA drained + WAR safety
  }

  // finalize ||w||^2 (sum over nj = lane bits 0..2)
  wn += __shfl_xor(wn, 1, 64);
  wn += __shfl_xor(wn, 2, 64);
  wn += __shfl_xor(wn, 4, 64);
  if (nj == 0) wlds[nr] = wn;
  __syncthreads();

  // epilogue: cos -> exp(64*cos-64), per-column partial sums
  float psum[4] = {0.f, 0.f, 0.f, 0.f};
#pragma unroll
  for (int ci = 0; ci < 4; ++ci) {
#pragma unroll
    for (int r = 0; r < 4; ++r) {
      const float n2  = wlds[ci * 16 + lk * 4 + r];
      const float inv = 1.0f / fmaxf(sqrtf(n2), 1e-12f);
#pragma unroll
      for (int bi = 0; bi < 4; ++bi) {
        float c = acc[ci][bi][r] * inv;
        c = fminf(fmaxf(c, -1.0f), 1.0f);
        psum[bi] += __expf(fmaf(SCL, c, -SCL));
      }
    }
  }
#pragma unroll
  for (int bi = 0; bi < 4; ++bi) {
    psum[bi] += __shfl_xor(psum[bi], 16, 64);
    psum[bi] += __shfl_xor(psum[bi], 32, 64);
  }
  if (lk == 0) {
#pragma unroll
    for (int bi = 0; bi < 4; ++bi)
      atomicAdd(&gsum[wave * 64 + bi * 16 + l15], psum[bi]);
  }
}

// --- k3: exact f32 target logit + margin + per-row NLL.
__global__ void k_target(const float* __restrict__ W,
                         const float* __restrict__ nf32,
                         const int* __restrict__ labels,
                         const float* __restrict__ gsum,
                         float* __restrict__ nll) {   // nll[0]=sum, nll[1]=count
  const int wave = threadIdx.x >> 6;
  const int lane = threadIdx.x & 63;
  const int b = blockIdx.x * 8 + wave;
  const int lab = labels[b];
  const bool valid = (lab >= 0);
  const int slab = valid ? lab : 0;
  const float* wr = W    + (size_t)slab * D_SZ;
  const float* er = nf32 + (size_t)b    * D_SZ;
  float dot = 0.f, wn2 = 0.f;
#pragma unroll
  for (int i = 0; i < 2; ++i) {
    const int d = i * 256 + lane * 4;
    float4 w4 = *(const float4*)(wr + d);
    float4 e4 = *(const float4*)(er + d);
    dot += w4.x*e4.x + w4.y*e4.y + w4.z*e4.z + w4.w*e4.w;
    wn2 += w4.x*w4.x + w4.y*w4.y + w4.z*w4.z + w4.w*w4.w;
  }
#pragma unroll
  for (int off = 32; off; off >>= 1) {
    dot += __shfl_xor(dot, off, 64);
    wn2 += __shfl_xor(wn2, off, 64);
  }
  if (lane == 0 && valid) {
    const float inv  = 1.0f / fmaxf(sqrtf(wn2), 1e-12f);
    float cost = fminf(fmaxf(dot * inv, -1.0f), 1.0f);
    const float th   = acosf(fminf(fmaxf(cost, -1.0f + 1e-7f), 1.0f - 1e-7f));
    const float newt = cosf(th + MRG);
    const float sum  = gsum[b] - expf(fmaf(SCL, cost, -SCL))
                               + expf(fmaf(SCL, newt, -SCL));
    const float lse  = logf(sum) + SCL;
    atomicAdd(&nll[0], lse - SCL * newt);
    atomicAdd(&nll[1], 1.0f);
  }
}

__global__ void k_final(const float* __restrict__ nll, float* __restrict__ out) {
  out[0] = nll[0] / fmaxf(nll[1], 1.0f);
}

// ---------------------------------------------------------------------------
extern "C" void kernel_launch(void* const* d_in, const int* in_sizes, int n_in,
                              void* d_out, int out_size, void* d_ws, size_t ws_size,
                              hipStream_t stream) {
  const float* emb    = (const float*)d_in[0];
  const int*   labels = (const int*)  d_in[1];
  const float* W      = (const float*)d_in[2];
  float* out = (float*)d_out;

  char* ws = (char*)d_ws;
  float*  nf32 = (float*)ws;                               // 1 MB
  ushort* nbf  = (ushort*)(ws + (1u << 20));               // 512 KB
  float*  gsum = (float*)(ws + (1u << 20) + (1u << 19));   // 2 KB
  float*  nll  = gsum + B_SZ;

  hipMemsetAsync(gsum, 0, (B_SZ + 2) * sizeof(float), stream);
  k_norm_emb<<<B_SZ / 4, 256, 0, stream>>>(emb, nf32, nbf);
  k_gemm_lse<<<C_SZ / BM, 512, 0, stream>>>(W, nbf, gsum);
  k_target<<<B_SZ / 8, 512, 0, stream>>>(W, nf32, labels, gsum, nll);
  k_final<<<1, 1, 0, stream>>>(nll, out);
}